// Round 1
// baseline (134.452 us; speedup 1.0000x reference)
//
#include <hip/hip_runtime.h>

#define SPATIAL_SCALE 0.0625f
#define PH 7
#define PW 7
#define SR 2

__global__ __launch_bounds__(256) void roi_align_kernel(
    const float* __restrict__ data,   // (B, C, H, W)
    const float* __restrict__ rois,   // (N, 5)
    float* __restrict__ out,          // (N, C, PH, PW)
    int C, int H, int W, int total)
{
    int idx = blockIdx.x * blockDim.x + threadIdx.x;
    if (idx >= total) return;

    int pw = idx % PW;
    int ph = (idx / PW) % PH;
    int c  = (idx / (PW * PH)) % C;
    int n  = idx / (PW * PH * C);

    const float* roi = rois + n * 5;
    int   b  = (int)roi[0];
    float x1 = roi[1] * SPATIAL_SCALE;
    float y1 = roi[2] * SPATIAL_SCALE;
    float x2 = roi[3] * SPATIAL_SCALE;
    float y2 = roi[4] * SPATIAL_SCALE;
    float roi_w = fmaxf(x2 - x1, 1.0f);
    float roi_h = fmaxf(y2 - y1, 1.0f);
    float bin_w = roi_w / (float)PW;
    float bin_h = roi_h / (float)PH;

    const float* base = data + (size_t)(b * C + c) * H * W;

    float acc = 0.0f;
    #pragma unroll
    for (int sy = 0; sy < SR; ++sy) {
        int iy = ph * SR + sy;
        float yc = y1 + (iy + 0.5f) * bin_h / (float)SR;
        bool  vy = (yc >= -1.0f) && (yc <= (float)H);
        float ycl = fminf(fmaxf(yc, 0.0f), (float)(H - 1));
        int   yl  = min(max((int)floorf(ycl), 0), H - 2);
        float ly  = ycl - (float)yl;
        float hy  = 1.0f - ly;
        #pragma unroll
        for (int sx = 0; sx < SR; ++sx) {
            int ix = pw * SR + sx;
            float xc = x1 + (ix + 0.5f) * bin_w / (float)SR;
            bool  vx = (xc >= -1.0f) && (xc <= (float)W);
            float xcl = fminf(fmaxf(xc, 0.0f), (float)(W - 1));
            int   xl  = min(max((int)floorf(xcl), 0), W - 2);
            float lx  = xcl - (float)xl;
            float hx  = 1.0f - lx;
            const float* p = base + yl * W + xl;
            float v = hy * hx * p[0] + hy * lx * p[1]
                    + ly * hx * p[W] + ly * lx * p[W + 1];
            acc += (vy && vx) ? v : 0.0f;
        }
    }
    out[idx] = acc * 0.25f;
}

extern "C" void kernel_launch(void* const* d_in, const int* in_sizes, int n_in,
                              void* d_out, int out_size, void* d_ws, size_t ws_size,
                              hipStream_t stream) {
    const float* data = (const float*)d_in[0];
    const float* rois = (const float*)d_in[1];
    float* out = (float*)d_out;

    // Shapes per reference setup: B=2, C=1024, H=50, W=50; N from rois size.
    const int C = 1024, H = 50, W = 50;
    const int N = in_sizes[1] / 5;
    const int total = N * C * PH * PW;   // == out_size

    dim3 block(256);
    dim3 grid((total + 255) / 256);
    roi_align_kernel<<<grid, block, 0, stream>>>(data, rois, out, C, H, W, total);
}

// Round 2
// 109.826 us; speedup vs baseline: 1.2242x; 1.2242x over previous
//
#include <hip/hip_runtime.h>

#define SPATIAL_SCALE 0.0625f
#define PH 7
#define PW 7
#define SR 2
#define C_TOTAL 1024
#define CPT 64                      // channels per thread
#define CHUNKS (C_TOTAL / CPT)      // 16

typedef float f4v __attribute__((ext_vector_type(4), aligned(8)));

__global__ __launch_bounds__(256) void roi_align_kernel(
    const float* __restrict__ data,   // (B, C, H, W)
    const float* __restrict__ rois,   // (N, 5)
    float* __restrict__ out,          // (N, C, PH, PW)
    int H, int W, int total_threads)
{
    int tid = blockIdx.x * blockDim.x + threadIdx.x;
    if (tid >= total_threads) return;

    // s fastest -> coalesced writes; then channel-chunk r; then roi n
    int s = tid % (PH * PW);
    int t2 = tid / (PH * PW);
    int r = t2 % CHUNKS;
    int n = t2 / CHUNKS;
    int pw = s % PW;
    int ph = s / PW;

    const float* roi = rois + n * 5;
    int   b  = (int)roi[0];
    float x1 = roi[1] * SPATIAL_SCALE;
    float y1 = roi[2] * SPATIAL_SCALE;
    float x2 = roi[3] * SPATIAL_SCALE;
    float y2 = roi[4] * SPATIAL_SCALE;
    float roi_w = fmaxf(x2 - x1, 1.0f);
    float roi_h = fmaxf(y2 - y1, 1.0f);
    float bin_w = roi_w * (1.0f / PW);
    float bin_h = roi_h * (1.0f / PH);

    // ---- x direction: 2 samples, taps collapse into a 4-wide window ----
    float xc0 = x1 + ((float)(pw * SR + 0) + 0.5f) * bin_w * (1.0f / SR);
    float xc1 = x1 + ((float)(pw * SR + 1) + 0.5f) * bin_w * (1.0f / SR);
    float vx0 = (xc0 >= -1.0f && xc0 <= (float)W) ? 1.0f : 0.0f;
    float vx1 = (xc1 >= -1.0f && xc1 <= (float)W) ? 1.0f : 0.0f;
    float xcl0 = fminf(fmaxf(xc0, 0.0f), (float)(W - 1));
    float xcl1 = fminf(fmaxf(xc1, 0.0f), (float)(W - 1));
    int xl0 = min(max((int)floorf(xcl0), 0), W - 2);
    int xl1 = min(max((int)floorf(xcl1), 0), W - 2);
    float lx0 = xcl0 - (float)xl0, hx0 = 1.0f - lx0;
    float lx1 = xcl1 - (float)xl1, hx1 = 1.0f - lx1;

    // even (8B-aligned) window base, clamped so xb+3 <= W-1
    int xb = min(xl0 & ~1, W - 4);
    int p0 = xl0 - xb;              // in {0,1,2}
    int p1 = xl1 - xb;              // in {0,1,2,3}, p1+1 <= 3 guaranteed

    float w4[4];
    #pragma unroll
    for (int k = 0; k < 4; ++k) {
        float a = (p0 == k) ? hx0 : ((p0 + 1 == k) ? lx0 : 0.0f);
        float c = (p1 == k) ? hx1 : ((p1 + 1 == k) ? lx1 : 0.0f);
        w4[k] = vx0 * a + vx1 * c;
    }

    // ---- y direction: 2 samples -> 4 rows with weights ----
    float yc0 = y1 + ((float)(ph * SR + 0) + 0.5f) * bin_h * (1.0f / SR);
    float yc1 = y1 + ((float)(ph * SR + 1) + 0.5f) * bin_h * (1.0f / SR);
    float vy0 = (yc0 >= -1.0f && yc0 <= (float)H) ? 1.0f : 0.0f;
    float vy1 = (yc1 >= -1.0f && yc1 <= (float)H) ? 1.0f : 0.0f;
    float ycl0 = fminf(fmaxf(yc0, 0.0f), (float)(H - 1));
    float ycl1 = fminf(fmaxf(yc1, 0.0f), (float)(H - 1));
    int yl0 = min(max((int)floorf(ycl0), 0), H - 2);
    int yl1 = min(max((int)floorf(ycl1), 0), H - 2);
    float ly0 = ycl0 - (float)yl0, hy0 = 1.0f - ly0;
    float ly1 = ycl1 - (float)yl1, hy1 = 1.0f - ly1;

    int rows0 = yl0, rows1 = yl0 + 1, rows2 = yl1, rows3 = yl1 + 1;
    float wy0 = 0.25f * vy0 * hy0;
    float wy1 = 0.25f * vy0 * ly0;
    float wy2 = 0.25f * vy1 * hy1;
    float wy3 = 0.25f * vy1 * ly1;

    // 4x4 combined weight matrix (mean + validity folded in)
    float wv[4][4];
    #pragma unroll
    for (int k = 0; k < 4; ++k) {
        wv[0][k] = wy0 * w4[k];
        wv[1][k] = wy1 * w4[k];
        wv[2][k] = wy2 * w4[k];
        wv[3][k] = wy3 * w4[k];
    }

    // ---- channel loop: 4 vector loads + 16 FMA per output ----
    int c0 = r * CPT;
    const int HW = H * W;
    unsigned slab = (unsigned)(b * C_TOTAL + c0) * (unsigned)HW;
    unsigned o0 = slab + (unsigned)(rows0 * W + xb);
    unsigned o1 = slab + (unsigned)(rows1 * W + xb);
    unsigned o2 = slab + (unsigned)(rows2 * W + xb);
    unsigned o3 = slab + (unsigned)(rows3 * W + xb);
    unsigned oo = (unsigned)((n * C_TOTAL + c0) * (PH * PW) + s);

    #pragma unroll 4
    for (int j = 0; j < CPT; ++j) {
        f4v r0 = *(const f4v*)(data + o0);
        f4v r1 = *(const f4v*)(data + o1);
        f4v r2 = *(const f4v*)(data + o2);
        f4v r3 = *(const f4v*)(data + o3);
        float acc = wv[0][0] * r0.x;
        acc += wv[0][1] * r0.y;  acc += wv[0][2] * r0.z;  acc += wv[0][3] * r0.w;
        acc += wv[1][0] * r1.x;  acc += wv[1][1] * r1.y;
        acc += wv[1][2] * r1.z;  acc += wv[1][3] * r1.w;
        acc += wv[2][0] * r2.x;  acc += wv[2][1] * r2.y;
        acc += wv[2][2] * r2.z;  acc += wv[2][3] * r2.w;
        acc += wv[3][0] * r3.x;  acc += wv[3][1] * r3.y;
        acc += wv[3][2] * r3.z;  acc += wv[3][3] * r3.w;
        out[oo] = acc;
        o0 += HW; o1 += HW; o2 += HW; o3 += HW;
        oo += PH * PW;
    }
}

extern "C" void kernel_launch(void* const* d_in, const int* in_sizes, int n_in,
                              void* d_out, int out_size, void* d_ws, size_t ws_size,
                              hipStream_t stream) {
    const float* data = (const float*)d_in[0];
    const float* rois = (const float*)d_in[1];
    float* out = (float*)d_out;

    const int H = 50, W = 50;
    const int N = in_sizes[1] / 5;
    const int total_threads = N * (PH * PW) * CHUNKS;   // 512*49*16 = 401408

    dim3 block(256);
    dim3 grid((total_threads + 255) / 256);
    roi_align_kernel<<<grid, block, 0, stream>>>(data, rois, out, H, W, total_threads);
}